// Round 8
// baseline (851.844 us; speedup 1.0000x reference)
//
#include <hip/hip_runtime.h>
#include <hip/hip_bf16.h>
#include <math.h>

#define NN 32768       // nodes
#define NE 524288      // edges
#define EN_TOT (NE + NN)
#define LL 8
#define SS 1025        // tokens (K+1)
#define SPLIT 16       // split-K for embedding gemm
#define SS128 (SS * 128)

// ---------------- CSR build ----------------
__global__ void hist_kernel(const int* __restrict__ ei, int* __restrict__ cnt) {
    int i = blockIdx.x * 256 + threadIdx.x;
    if (i >= EN_TOT) return;
    int d = (i < NE) ? ei[NE + i] : (i - NE);
    atomicAdd(&cnt[d], 1);
}

__global__ void scan_kernel(const int* __restrict__ cnt, int* __restrict__ offs) {
    __shared__ int wsum[16];
    int t = threadIdx.x;              // 0..1023, each owns 32 elements
    int base = t * 32;
    int s = 0;
    #pragma unroll
    for (int j = 0; j < 32; ++j) s += cnt[base + j];
    int lane = t & 63, w = t >> 6;
    int v = s;
    #pragma unroll
    for (int d = 1; d < 64; d <<= 1) {
        int u = __shfl_up(v, d);
        if (lane >= d) v += u;
    }
    if (lane == 63) wsum[w] = v;
    __syncthreads();
    if (t == 0) {
        int a = 0;
        #pragma unroll
        for (int i = 0; i < 16; ++i) { int x = wsum[i]; wsum[i] = a; a += x; }
    }
    __syncthreads();
    int run = wsum[w] + (v - s);
    #pragma unroll
    for (int j = 0; j < 32; ++j) { offs[base + j] = run; run += cnt[base + j]; }
    if (t == 1023) offs[NN] = run;
}

__global__ void scatter_kernel(const int* __restrict__ ei, const int* __restrict__ offs,
                               int* __restrict__ fill, int* __restrict__ csr) {
    int i = blockIdx.x * 256 + threadIdx.x;
    if (i >= EN_TOT) return;
    int s, d;
    if (i < NE) { s = ei[i]; d = ei[NE + i]; } else { s = d = i - NE; }
    int pos = offs[d] + atomicAdd(&fill[d], 1);
    csr[pos] = s;
}

// ---------------- generic fp32 GEMM (round-3 form, deterministic) ----------------
__device__ __forceinline__ float gelu_f(float x) {
    float x3 = x * x * x;
    return 0.5f * x * (1.f + tanhf(0.7978845608028654f * (x + 0.044715f * x3)));
}

__global__ void gemm_f32(const float* __restrict__ A, const float* __restrict__ B,
                         const float* __restrict__ bias, const float* res,
                         float* C, int M, int Nn, int K) {
    __shared__ float As[32][66];
    __shared__ float Bs[32][72];
    int t = threadIdx.x;
    int bx = blockIdx.x, by = blockIdx.y;
    int tx = t & 15, ty = t >> 4;
    float acc[4][4] = {};
    int m0 = t >> 3;
    int kk4 = (t & 7) * 4;
    int kb0 = t >> 4;
    int n40 = (t & 15) * 4;

    for (int k0 = 0; k0 < K; k0 += 32) {
        __syncthreads();
        #pragma unroll
        for (int half = 0; half < 2; ++half) {
            int m = m0 + half * 32;
            int row = by * 64 + m;
            float4 v = {0.f, 0.f, 0.f, 0.f};
            if (row < M) v = *(const float4*)&A[(size_t)row * K + k0 + kk4];
            As[kk4 + 0][m] = v.x; As[kk4 + 1][m] = v.y;
            As[kk4 + 2][m] = v.z; As[kk4 + 3][m] = v.w;
        }
        #pragma unroll
        for (int half = 0; half < 2; ++half) {
            int kk = kb0 + half * 16;
            *(float4*)&Bs[kk][n40] = *(const float4*)&B[(size_t)(k0 + kk) * Nn + bx * 64 + n40];
        }
        __syncthreads();
        #pragma unroll
        for (int kk = 0; kk < 32; ++kk) {
            float a0 = As[kk][ty * 4 + 0];
            float a1 = As[kk][ty * 4 + 1];
            float a2 = As[kk][ty * 4 + 2];
            float a3 = As[kk][ty * 4 + 3];
            float4 b4 = *(float4*)&Bs[kk][tx * 4];
            acc[0][0] += a0 * b4.x; acc[0][1] += a0 * b4.y; acc[0][2] += a0 * b4.z; acc[0][3] += a0 * b4.w;
            acc[1][0] += a1 * b4.x; acc[1][1] += a1 * b4.y; acc[1][2] += a1 * b4.z; acc[1][3] += a1 * b4.w;
            acc[2][0] += a2 * b4.x; acc[2][1] += a2 * b4.y; acc[2][2] += a2 * b4.z; acc[2][3] += a2 * b4.w;
            acc[3][0] += a3 * b4.x; acc[3][1] += a3 * b4.y; acc[3][2] += a3 * b4.z; acc[3][3] += a3 * b4.w;
        }
    }
    #pragma unroll
    for (int i = 0; i < 4; ++i) {
        int row = by * 64 + ty * 4 + i;
        if (row < M) {
            #pragma unroll
            for (int j = 0; j < 4; ++j) {
                int col = bx * 64 + tx * 4 + j;
                float v = acc[i][j];
                if (bias) v += bias[col];
                if (res) v += res[(size_t)row * Nn + col];
                C[(size_t)row * Nn + col] = v;
            }
        }
    }
}

__global__ void bcomb_kernel(const float* __restrict__ b_in, const float* __restrict__ Wg1,
                             float* __restrict__ bcomb) {
    int n = threadIdx.x;  // 128
    float s = 0.f;
    for (int k = 0; k < 128; ++k) s += b_in[k] * Wg1[k * 128 + n];
    bcomb[n] = s;
}

// ---------------- GAT attention dots (round-3 form, deterministic) ----------------
__global__ void dots_kernel(const float* __restrict__ hW, const float* __restrict__ asrc,
                            const float* __restrict__ adst, float* __restrict__ ss,
                            float* __restrict__ sd) {
    int lane = threadIdx.x & 63;
    int n = blockIdx.x * 4 + (threadIdx.x >> 6);
    float h0 = hW[(size_t)n * 128 + lane];
    float h1 = hW[(size_t)n * 128 + 64 + lane];
    float vs = h0 * asrc[lane] + h1 * asrc[64 + lane];
    float vd = h0 * adst[lane] + h1 * adst[64 + lane];
    #pragma unroll
    for (int m = 32; m >= 1; m >>= 1) { vs += __shfl_xor(vs, m); vd += __shfl_xor(vd, m); }
    if (lane == 0) { ss[n] = vs; sd[n] = vd; }
}

// ---------------- GAT aggregation: fp32, strict csr-order serial sum (round-3 numerics),
// lane-parallel alphas + shfl broadcast + 4-row pipeline. Lane owns dims {2l, 2l+1}.
__global__ void gat_aggregate(const float* __restrict__ hW, const int* __restrict__ offs,
                              const int* __restrict__ csr, const float* __restrict__ ssrc,
                              const float* __restrict__ sdst, const float* __restrict__ bias,
                              float* __restrict__ out) {
    int lane = threadIdx.x & 63;
    int n = blockIdx.x * 4 + (threadIdx.x >> 6);
    int beg = offs[n], end = offs[n + 1];   // deg >= 1 (self loop)
    float sd = sdst[n];
    float mymax = -INFINITY;
    for (int p = beg + lane; p < end; p += 64) {
        float e = ssrc[csr[p]] + sd;
        e = (e >= 0.f) ? e : 0.2f * e;
        mymax = fmaxf(mymax, e);
    }
    #pragma unroll
    for (int m = 32; m >= 1; m >>= 1) mymax = fmaxf(mymax, __shfl_xor(mymax, m));
    float mysum = 0.f;
    for (int p = beg + lane; p < end; p += 64) {
        float e = ssrc[csr[p]] + sd;
        e = (e >= 0.f) ? e : 0.2f * e;
        mysum += __expf(e - mymax);
    }
    #pragma unroll
    for (int m = 32; m >= 1; m >>= 1) mysum += __shfl_xor(mysum, m);
    float inv = 1.f / mysum;
    // pass 3: per-dim serial accumulation in csr order (bitwise round-3), 4 rows in flight
    float accx = 0.f, accy = 0.f;
    int deg = end - beg;
    for (int c0 = 0; c0 < deg; c0 += 64) {
        int s = 0; float al = 0.f;
        if (c0 + lane < deg) {
            s = csr[beg + c0 + lane];
            float e = ssrc[s] + sd;
            e = (e >= 0.f) ? e : 0.2f * e;
            al = __expf(e - mymax) * inv;
        }
        int cend = min(64, deg - c0);
        int p = 0;
        for (; p + 4 <= cend; p += 4) {
            int s0 = __shfl(s, p);     float a0 = __shfl(al, p);
            int s1 = __shfl(s, p + 1); float a1 = __shfl(al, p + 1);
            int s2 = __shfl(s, p + 2); float a2 = __shfl(al, p + 2);
            int s3 = __shfl(s, p + 3); float a3 = __shfl(al, p + 3);
            float2 v0 = *(const float2*)&hW[(size_t)s0 * 128 + lane * 2];
            float2 v1 = *(const float2*)&hW[(size_t)s1 * 128 + lane * 2];
            float2 v2 = *(const float2*)&hW[(size_t)s2 * 128 + lane * 2];
            float2 v3 = *(const float2*)&hW[(size_t)s3 * 128 + lane * 2];
            accx += a0 * v0.x; accy += a0 * v0.y;
            accx += a1 * v1.x; accy += a1 * v1.y;
            accx += a2 * v2.x; accy += a2 * v2.y;
            accx += a3 * v3.x; accy += a3 * v3.y;
        }
        for (; p < cend; ++p) {
            int sj = __shfl(s, p);
            float aj = __shfl(al, p);
            float2 v = *(const float2*)&hW[(size_t)sj * 128 + lane * 2];
            accx += aj * v.x; accy += aj * v.y;
        }
    }
    float2 ov;
    ov.x = accx + bias[2 * lane];
    ov.y = accy + bias[2 * lane + 1];
    *(float2*)&out[(size_t)n * 128 + 2 * lane] = ov;
}

// ---------------- cluster gather (coalesced) + split-K embedding GEMM ----------------
__global__ void gather_copy(const float* __restrict__ hA, const int* __restrict__ no,
                            float* __restrict__ flat) {
    int i = blockIdx.x * 256 + threadIdx.x;   // 0 .. 4194303
    int m = i >> 12, j = i & 4095;
    int node = no[(m << 5) + (j >> 7)];
    flat[i] = hA[(size_t)node * 128 + (j & 127)];
}

__global__ void emb_gemm(const float* __restrict__ flat, const float* __restrict__ W,
                         float* __restrict__ pbuf) {
    __shared__ float As[32][66];
    __shared__ float Bs[32][72];
    int t = threadIdx.x;
    int bx = blockIdx.x, by = blockIdx.y, sp = blockIdx.z;
    int tx = t & 15, ty = t >> 4;
    float acc[4][4] = {};
    int m0 = t >> 3;
    int kk4 = (t & 7) * 4;
    int kb0 = t >> 4;
    int n40 = (t & 15) * 4;
    int kbase = sp * 256;

    for (int k0 = 0; k0 < 256; k0 += 32) {
        __syncthreads();
        #pragma unroll
        for (int half = 0; half < 2; ++half) {
            int m = m0 + half * 32;
            int row = by * 64 + m;
            float4 v = *(const float4*)&flat[(size_t)row * 4096 + kbase + k0 + kk4];
            As[kk4 + 0][m] = v.x; As[kk4 + 1][m] = v.y;
            As[kk4 + 2][m] = v.z; As[kk4 + 3][m] = v.w;
        }
        #pragma unroll
        for (int half = 0; half < 2; ++half) {
            int kk = kb0 + half * 16;
            *(float4*)&Bs[kk][n40] = *(const float4*)&W[(size_t)(kbase + k0 + kk) * 128 + bx * 64 + n40];
        }
        __syncthreads();
        #pragma unroll
        for (int kk = 0; kk < 32; ++kk) {
            float a0 = As[kk][ty * 4 + 0];
            float a1 = As[kk][ty * 4 + 1];
            float a2 = As[kk][ty * 4 + 2];
            float a3 = As[kk][ty * 4 + 3];
            float4 b4 = *(float4*)&Bs[kk][tx * 4];
            acc[0][0] += a0 * b4.x; acc[0][1] += a0 * b4.y; acc[0][2] += a0 * b4.z; acc[0][3] += a0 * b4.w;
            acc[1][0] += a1 * b4.x; acc[1][1] += a1 * b4.y; acc[1][2] += a1 * b4.z; acc[1][3] += a1 * b4.w;
            acc[2][0] += a2 * b4.x; acc[2][1] += a2 * b4.y; acc[2][2] += a2 * b4.z; acc[2][3] += a2 * b4.w;
            acc[3][0] += a3 * b4.x; acc[3][1] += a3 * b4.y; acc[3][2] += a3 * b4.z; acc[3][3] += a3 * b4.w;
        }
    }
    float* C = pbuf + (size_t)sp * (1024 * 128);
    #pragma unroll
    for (int i = 0; i < 4; ++i) {
        int row = by * 64 + ty * 4 + i;
        #pragma unroll
        for (int j = 0; j < 4; ++j)
            C[(size_t)row * 128 + bx * 64 + tx * 4 + j] = acc[i][j];
    }
}

// emb_reduce + cls token write (fused); fixed sp order -> deterministic
__global__ void emb_reduce(const float* __restrict__ pbuf, const float* __restrict__ b_emb,
                           const float* __restrict__ cls, float* __restrict__ tb) {
    int i = blockIdx.x * 256 + threadIdx.x;   // 0..131071
    if (blockIdx.x == 0 && threadIdx.x < 128) tb[threadIdx.x] = cls[threadIdx.x];
    float s = b_emb[i & 127];
    #pragma unroll
    for (int sp = 0; sp < SPLIT; ++sp) s += pbuf[(size_t)sp * 131072 + i];
    tb[128 + i] = s;
}

// ---------------- transformer kernels (deterministic: FFN partials in P, fixed-order combine) ----------------
// Effective token state = tb[row] + P[0][row] + P[1][row] + P[2][row] + P[3][row].
__device__ __forceinline__ float tok_read(const float* __restrict__ tb, const float* __restrict__ P,
                                          size_t ix) {
    return tb[ix] + P[ix] + P[SS128 + ix] + P[2 * (size_t)SS128 + ix] + P[3 * (size_t)SS128 + ix];
}

// QKV col-slice: grid (257, 3). u = LN1(tok); qkv[:, sl*128:+128] = u@Wq_sl + bq_sl
__global__ __launch_bounds__(256) void qkv_slice(
        const float* __restrict__ tb, const float* __restrict__ P,
        const float* __restrict__ s1, const float* __restrict__ b1,
        const float* __restrict__ Wq, const float* __restrict__ bq, float* __restrict__ qkv) {
    __shared__ float u[4][128];
    __shared__ float red[4][2][128];
    __shared__ float ws[8192];   // 32 KB: 64 k-rows x 128 cols
    int t = threadIdx.x;
    int r0 = blockIdx.x * 4, sl = blockIdx.y;
    int col = t & 127, kh = t >> 7;
    {   // LN1: 64 lanes per row
        int rw = t >> 6, lane = t & 63;
        int row = r0 + rw;
        float a0 = 0.f, a1 = 0.f;
        if (row < SS) {
            size_t ix = (size_t)row * 128 + lane;
            a0 = tok_read(tb, P, ix);
            a1 = tok_read(tb, P, ix + 64);
        }
        float sm = a0 + a1;
        #pragma unroll
        for (int m = 32; m >= 1; m >>= 1) sm += __shfl_xor(sm, m);
        float mean = sm * (1.f / 128.f);
        float d0 = a0 - mean, d1 = a1 - mean;
        float vv = d0 * d0 + d1 * d1;
        #pragma unroll
        for (int m = 32; m >= 1; m >>= 1) vv += __shfl_xor(vv, m);
        float rs = rsqrtf(vv * (1.f / 128.f) + 1e-5f);
        u[rw][lane] = d0 * rs * s1[lane] + b1[lane];
        u[rw][64 + lane] = d1 * rs * s1[64 + lane] + b1[64 + lane];
    }
    float acc[4] = {};
    for (int k0 = 0; k0 < 128; k0 += 64) {
        __syncthreads();
        const float* src = Wq + (size_t)k0 * 384 + sl * 128;
        #pragma unroll
        for (int i = 0; i < 8; ++i) {
            int idx = i * 256 + t;          // float4 index, 32 per k-row
            int kk = idx >> 5, c4 = (idx & 31) * 4;
            ((float4*)ws)[idx] = *(const float4*)&src[(size_t)kk * 384 + c4];
        }
        __syncthreads();
        int kb = kh * 32;
        #pragma unroll
        for (int kq = 0; kq < 32; kq += 4) {
            float a4[4][4];
            #pragma unroll
            for (int i = 0; i < 4; ++i)
                *(float4*)a4[i] = *(const float4*)&u[i][k0 + kb + kq];
            #pragma unroll
            for (int q = 0; q < 4; ++q) {
                float b = ws[(kb + kq + q) * 128 + col];
                #pragma unroll
                for (int i = 0; i < 4; ++i) acc[i] += a4[i][q] * b;
            }
        }
    }
    __syncthreads();
    #pragma unroll
    for (int i = 0; i < 4; ++i) red[i][kh][col] = acc[i];
    __syncthreads();
    if (t < 128) {
        float bqv = bq[sl * 128 + t];
        #pragma unroll
        for (int i = 0; i < 4; ++i) {
            int row = r0 + i;
            if (row < SS)
                qkv[(size_t)row * 384 + sl * 128 + t] = red[i][0][t] + red[i][1][t] + bqv;
        }
    }
}

// proj + residual + LN2: tn = o@Wo + bo + tok; tb = tn + bf2 (FFN P's added by consumers); ub = LN2(tn)
__global__ __launch_bounds__(256) void proj_ln2(
        const float* __restrict__ ao, const float* __restrict__ P,
        const float* __restrict__ Wo, const float* __restrict__ bo,
        const float* __restrict__ s2, const float* __restrict__ b2, const float* __restrict__ bf2,
        float* __restrict__ tb, float* __restrict__ ub) {
    __shared__ float bufA[4][128];
    __shared__ float tn[4][128];
    __shared__ float red[4][2][128];
    __shared__ float ws[8192];
    int t = threadIdx.x;
    int r0 = blockIdx.x * 4;
    int lane = t & 63;
    int col = t & 127, kh = t >> 7;
    {   // stage o rows
        int rw = t >> 6;
        int row = r0 + rw;
        float a0 = 0.f, a1 = 0.f;
        if (row < SS) {
            a0 = ao[(size_t)row * 128 + lane];
            a1 = ao[(size_t)row * 128 + 64 + lane];
        }
        bufA[rw][lane] = a0;
        bufA[rw][64 + lane] = a1;
    }
    float pp[4] = {};
    for (int k0 = 0; k0 < 128; k0 += 64) {
        __syncthreads();
        const float4* src = (const float4*)&Wo[(size_t)k0 * 128];
        #pragma unroll
        for (int i = 0; i < 8; ++i) ((float4*)ws)[i * 256 + t] = src[i * 256 + t];
        __syncthreads();
        int kb = kh * 32;
        #pragma unroll
        for (int kq = 0; kq < 32; kq += 4) {
            float a4[4][4];
            #pragma unroll
            for (int i = 0; i < 4; ++i)
                *(float4*)a4[i] = *(const float4*)&bufA[i][k0 + kb + kq];
            #pragma unroll
            for (int q = 0; q < 4; ++q) {
                float b = ws[(kb + kq + q) * 128 + col];
                #pragma unroll
                for (int i = 0; i < 4; ++i) pp[i] += a4[i][q] * b;
            }
        }
    }
    __syncthreads();
    #pragma unroll
    for (int i = 0; i < 4; ++i) red[i][kh][col] = pp[i];
    __syncthreads();
    if (t < 128) {
        #pragma unroll
        for (int i = 0; i < 4; ++i) {
            int row = r0 + i;
            float v = 0.f;
            if (row < SS) {
                size_t ix = (size_t)row * 128 + t;
                float told = tok_read(tb, P, ix);
                v = red[i][0][t] + red[i][1][t] + bo[t] + told;
                tb[ix] = v + bf2[t];   // P slices (overwritten by this layer's ffn) complete it
            }
            tn[i][t] = v;
        }
    }
    __syncthreads();
    {   // LN2(tn) -> ub
        int rw = t >> 6;
        int row = r0 + rw;
        float a0 = tn[rw][lane], a1 = tn[rw][64 + lane];
        float sm = a0 + a1;
        #pragma unroll
        for (int m = 32; m >= 1; m >>= 1) sm += __shfl_xor(sm, m);
        float mean = sm * (1.f / 128.f);
        float d0 = a0 - mean, d1 = a1 - mean;
        float vv = d0 * d0 + d1 * d1;
        #pragma unroll
        for (int m = 32; m >= 1; m >>= 1) vv += __shfl_xor(vv, m);
        float rs = rsqrtf(vv * (1.f / 128.f) + 1e-5f);
        if (row < SS) {
            ub[(size_t)row * 128 + lane] = d0 * rs * s2[lane] + b2[lane];
            ub[(size_t)row * 128 + 64 + lane] = d1 * rs * s2[64 + lane] + b2[64 + lane];
        }
    }
}

// FFN hidden-slice: grid (257, 4). g = gelu(u@Wf1[:,sl]+bf1[sl]); P[sl] = g@Wf2[sl,:]  (plain stores)
__global__ __launch_bounds__(256) void ffn_part(
        const float* __restrict__ ub, const float* __restrict__ Wf1, const float* __restrict__ bf1,
        const float* __restrict__ Wf2, float* __restrict__ P) {
    __shared__ float u[4][128];
    __shared__ float g[4][128];
    __shared__ float red[4][2][128];
    __shared__ float ws[8192];
    int t = threadIdx.x;
    int r0 = blockIdx.x * 4, sl = blockIdx.y;
    int col = t & 127, kh = t >> 7;
    {   // load u rows
        int rw = t >> 6, lane = t & 63;
        int row = r0 + rw;
        float a0 = 0.f, a1 = 0.f;
        if (row < SS) {
            a0 = ub[(size_t)row * 128 + lane];
            a1 = ub[(size_t)row * 128 + 64 + lane];
        }
        u[rw][lane] = a0;
        u[rw][64 + lane] = a1;
    }
    // ffn1 slice
    float a1c[4] = {};
    for (int k0 = 0; k0 < 128; k0 += 64) {
        __syncthreads();
        const float* src = Wf1 + (size_t)k0 * 512 + sl * 128;
        #pragma unroll
        for (int i = 0; i < 8; ++i) {
            int idx = i * 256 + t;
            int kk = idx >> 5, c4 = (idx & 31) * 4;
            ((float4*)ws)[idx] = *(const float4*)&src[(size_t)kk * 512 + c4];
        }
        __syncthreads();
        int kb = kh * 32;
        #pragma unroll
        for (int kq = 0; kq < 32; kq += 4) {
            float a4[4][4];
            #pragma unroll
            for (int i = 0; i < 4; ++i)
                *(float4*)a4[i] = *(const float4*)&u[i][k0 + kb + kq];
            #pragma unroll
            for (int q = 0; q < 4; ++q) {
                float b = ws[(kb + kq + q) * 128 + col];
                #pragma unroll
                for (int i = 0; i < 4; ++i) a1c[i] += a4[i][q] * b;
            }
        }
    }
    __syncthreads();
    #pragma unroll
    for (int i = 0; i < 4; ++i) red[i][kh][col] = a1c[i];
    __syncthreads();
    if (t < 128) {
        float bv = bf1[sl * 128 + t];
        #pragma unroll
        for (int i = 0; i < 4; ++i)
            g[i][t] = gelu_f(red[i][0][t] + red[i][1][t] + bv);
    }
    // ffn2 slice: Wf2 rows [sl*128, sl*128+128) contiguous
    float a2c[4] = {};
    for (int k0 = 0; k0 < 128; k0 += 64) {
        __syncthreads();
        const float4* src = (const float4*)&Wf2[(size_t)(sl * 128 + k0) * 128];
        #pragma unroll
        for (int i = 0; i < 8; ++i) ((float4*)ws)[i * 256 + t] = src[i * 256 + t];
        __syncthreads();
        int kb = kh * 32;
        #pragma unroll
        for (int kq = 0; kq < 32; kq += 4) {
            float a4[4][4];
            #pragma unroll
            for (int i = 0; i < 4; ++i)
                *(float4*)a4[i] = *(const float4*)&g[i][k0 + kb + kq];
            #pragma unroll
            for (int q = 0; q < 4; ++q) {
                float b = ws[(kb + kq + q) * 128 + col];
                #pragma unroll
                for (int i = 0; i < 4; ++i) a2c[i] += a4[i][q] * b;
            }
        }
    }
    __syncthreads();
    #pragma unroll
    for (int i = 0; i < 4; ++i) red[i][kh][col] = a2c[i];
    __syncthreads();
    if (t < 128) {
        #pragma unroll
        for (int i = 0; i < 4; ++i) {
            int row = r0 + i;
            if (row < SS)
                P[(size_t)sl * SS128 + (size_t)row * 128 + t] = red[i][0][t] + red[i][1][t];
        }
    }
}

// flash attention: dh=16, 16 lanes per query row, 128-key tiles in LDS
__global__ void attn_kernel(const float* __restrict__ qkv, float* __restrict__ ao) {
    __shared__ float Kl[128][20];
    __shared__ float Vl[128][20];
    int h = blockIdx.y;
    int t = threadIdx.x;
    int sub = t & 15;
    int qr = blockIdx.x * 16 + (t >> 4);
    bool active = qr < SS;
    float q[16];
    if (active) {
        #pragma unroll
        for (int d = 0; d < 16; ++d) q[d] = qkv[(size_t)qr * 384 + h * 16 + d];
    }
    float m = -INFINITY, sum = 0.f;
    float acc[16] = {};
    for (int j0 = 0; j0 < SS; j0 += 128) {
        __syncthreads();
        int j = t >> 1, dg = (t & 1) * 8;   // 256 threads stage 128 rows x 16 floats
        if (j0 + j < SS) {
            const float* row = qkv + (size_t)(j0 + j) * 384 + h * 16 + dg;
            *(float4*)&Kl[j][dg]     = *(const float4*)(row + 128);
            *(float4*)&Kl[j][dg + 4] = *(const float4*)(row + 132);
            *(float4*)&Vl[j][dg]     = *(const float4*)(row + 256);
            *(float4*)&Vl[j][dg + 4] = *(const float4*)(row + 260);
        }
        __syncthreads();
        if (active) {
            int jmax = min(128, SS - j0);
            for (int jj = sub; jj < jmax; jj += 16) {
                float4 ka = *(const float4*)&Kl[jj][0];
                float4 kb = *(const float4*)&Kl[jj][4];
                float4 kc = *(const float4*)&Kl[jj][8];
                float4 kd = *(const float4*)&Kl[jj][12];
                float sc = q[0]*ka.x + q[1]*ka.y + q[2]*ka.z + q[3]*ka.w
                         + q[4]*kb.x + q[5]*kb.y + q[6]*kb.z + q[7]*kb.w
                         + q[8]*kc.x + q[9]*kc.y + q[10]*kc.z + q[11]*kc.w
                         + q[12]*kd.x + q[13]*kd.y + q[14]*kd.z + q[15]*kd.w;
                sc *= 0.25f;
                float4 va = *(const float4*)&Vl[jj][0];
                float4 vb = *(const float4*)&Vl[jj][4];
                float4 vc = *(const float4*)&Vl[jj][8];
                float4 vd = *(const float4*)&Vl[jj][12];
                float vv[16] = {va.x, va.y, va.z, va.w, vb.x, vb.y, vb.z, vb.w,
                                vc.x, vc.y, vc.z, vc.w, vd.x, vd.y, vd.z, vd.w};
                if (sc <= m) {
                    float p = __expf(sc - m);
                    sum += p;
                    #pragma unroll
                    for (int d = 0; d < 16; ++d) acc[d] += p * vv[d];
                } else {
                    float c = __expf(m - sc);
                    sum = sum * c + 1.f;
                    #pragma unroll
                    for (int d = 0; d < 16; ++d) acc[d] = acc[d] * c + vv[d];
                    m = sc;
                }
            }
        }
    }
    if (active) {
        #pragma unroll
        for (int msk = 1; msk < 16; msk <<= 1) {
            float mo = __shfl_xor(m, msk);
            float so = __shfl_xor(sum, msk);
            float vo[16];
            #pragma unroll
            for (int d = 0; d < 16; ++d) vo[d] = __shfl_xor(acc[d], msk);
            float mn = fmaxf(m, mo);
            float c1 = __expf(m - mn), c2 = __expf(mo - mn);
            sum = sum * c1 + so * c2;
            #pragma unroll
            for (int d = 0; d < 16; ++d) acc[d] = acc[d] * c1 + vo[d] * c2;
            m = mn;
        }
        if (sub == 0) {
            float inv = 1.f / sum;
            #pragma unroll
            for (int d = 0; d < 16; ++d) ao[(size_t)qr * 128 + h * 16 + d] = acc[d] * inv;
        }
    }
}

__global__ void classifier_kernel(const float* __restrict__ tb, const float* __restrict__ P,
                                  const float* __restrict__ Wc, const float* __restrict__ bc,
                                  float* __restrict__ out) {
    int j = threadIdx.x;
    if (j < 10) {
        float a = bc[j];
        #pragma unroll
        for (int k = 0; k < 128; ++k) a += tok_read(tb, P, k) * Wc[k * 10 + j];
        out[j] = a;
    }
}

// ---------------- launch ----------------
extern "C" void kernel_launch(void* const* d_in, const int* in_sizes, int n_in,
                              void* d_out, int out_size, void* d_ws, size_t ws_size,
                              hipStream_t stream) {
    (void)in_sizes; (void)n_in; (void)out_size; (void)ws_size;
    const float* x     = (const float*)d_in[0];
    const int*   ei    = (const int*)d_in[1];
    const int*   nord  = (const int*)d_in[2];
    const float* W_in  = (const float*)d_in[3];
    const float* b_in  = (const float*)d_in[4];
    const float* Wg1   = (const float*)d_in[5];
    const float* as1   = (const float*)d_in[6];
    const float* ad1   = (const float*)d_in[7];
    const float* bg1   = (const float*)d_in[8];
    const float* Wg2   = (const float*)d_in[9];
    const float* as2   = (const float*)d_in[10];
    const float* ad2   = (const float*)d_in[11];
    const float* bg2   = (const float*)d_in[12];
    const float* W_emb = (const float*)d_in[13];
    const float* b_emb = (const float*)d_in[14];
    const float* clst  = (const float*)d_in[15];
    const float* ln1s  = (const float*)d_in[16];
    const float* ln1b  = (const float*)d_in[17];
    const float* Wqkv  = (const float*)d_in[18];
    const float* bqkv  = (const float*)d_in[19];
    const float* Wo    = (const float*)d_in[20];
    const float* bo    = (const float*)d_in[21];
    const float* ln2s  = (const float*)d_in[22];
    const float* ln2b  = (const float*)d_in[23];
    const float* Wf1   = (const float*)d_in[24];
    const float* bf1   = (const float*)d_in[25];
    const float* Wf2   = (const float*)d_in[26];
    const float* bf2   = (const float*)d_in[27];
    const float* Wc    = (const float*)d_in[28];
    const float* bc    = (const float*)d_in[29];

    char* w = (char*)d_ws;
    size_t o = 0;
    auto ALLOC = [&](size_t nbytes) -> char* {
        char* p = w + o;
        o += (nbytes + 255) & ~(size_t)255;
        return p;
    };
    int*   cnt   = (int*)ALLOC((size_t)NN * 4);
    int*   fill  = (int*)ALLOC((size_t)NN * 4);            // contiguous with cnt
    int*   offs  = (int*)ALLOC((size_t)(NN + 1) * 4);
    int*   csr   = (int*)ALLOC((size_t)EN_TOT * 4);
    float* hA    = (float*)ALLOC((size_t)NN * 128 * 4);    // GAT2 output
    float* hW    = (float*)ALLOC((size_t)NN * 128 * 4);    // also pbuf
    float* h1    = (float*)ALLOC((size_t)NN * 128 * 4);    // also flat (16MB)
    float* ssrc  = (float*)ALLOC((size_t)NN * 4);
    float* sdst  = (float*)ALLOC((size_t)NN * 4);
    float* tbuf  = (float*)ALLOC((size_t)SS128 * 4);
    float* ubuf  = (float*)ALLOC((size_t)SS128 * 4);
    float* qkvb  = (float*)ALLOC((size_t)SS * 384 * 4);
    float* aob   = (float*)ALLOC((size_t)SS128 * 4);
    float* Pbuf  = (float*)ALLOC((size_t)4 * SS128 * 4);   // FFN partials
    float* Wcomb = (float*)ALLOC((size_t)128 * 128 * 4);
    float* bcomb = (float*)ALLOC((size_t)128 * 4);
    float* pbuf  = hW;
    float* flat  = h1;

    dim3 blk(256);
    int egrid = (EN_TOT + 255) / 256;

    // CSR by dst
    hipMemsetAsync(cnt, 0, (size_t)NN * 8, stream);
    hist_kernel<<<egrid, blk, 0, stream>>>(ei, cnt);
    scan_kernel<<<1, 1024, 0, stream>>>(cnt, offs);
    scatter_kernel<<<egrid, blk, 0, stream>>>(ei, offs, fill, csr);

    // Wcomb = W_in@Wg1 ; bcomb = b_in@Wg1
    gemm_f32<<<dim3(2, 2), blk, 0, stream>>>(W_in, Wg1, nullptr, nullptr, Wcomb, 128, 128, 128);
    bcomb_kernel<<<1, 128, 0, stream>>>(b_in, Wg1, bcomb);

    // GAT 1
    gemm_f32<<<dim3(2, 512), blk, 0, stream>>>(x, Wcomb, bcomb, nullptr, hW, NN, 128, 128);
    dots_kernel<<<8192, blk, 0, stream>>>(hW, as1, ad1, ssrc, sdst);
    gat_aggregate<<<8192, blk, 0, stream>>>(hW, offs, csr, ssrc, sdst, bg1, h1);
    // GAT 2
    gemm_f32<<<dim3(2, 512), blk, 0, stream>>>(h1, Wg2, nullptr, nullptr, hW, NN, 128, 128);
    dots_kernel<<<8192, blk, 0, stream>>>(hW, as2, ad2, ssrc, sdst);
    gat_aggregate<<<8192, blk, 0, stream>>>(hW, offs, csr, ssrc, sdst, bg2, hA);

    // tokens
    gather_copy<<<16384, blk, 0, stream>>>(hA, nord, flat);
    emb_gemm<<<dim3(2, 16, SPLIT), blk, 0, stream>>>(flat, W_emb, pbuf);
    emb_reduce<<<512, blk, 0, stream>>>(pbuf, b_emb, clst, tbuf);

    // FFN partial buffers start at zero (layer-0 consumers read them)
    hipMemsetAsync(Pbuf, 0, (size_t)4 * SS128 * 4, stream);

    for (int l = 0; l < LL; ++l) {
        qkv_slice<<<dim3(257, 3), blk, 0, stream>>>(tbuf, Pbuf, ln1s + l * 128, ln1b + l * 128,
                                                    Wqkv + (size_t)l * 128 * 384, bqkv + l * 384, qkvb);
        attn_kernel<<<dim3(65, 8), blk, 0, stream>>>(qkvb, aob);
        proj_ln2<<<257, blk, 0, stream>>>(aob, Pbuf, Wo + (size_t)l * 128 * 128, bo + l * 128,
                                          ln2s + l * 128, ln2b + l * 128, bf2 + l * 128,
                                          tbuf, ubuf);
        ffn_part<<<dim3(257, 4), blk, 0, stream>>>(ubuf, Wf1 + (size_t)l * 128 * 512, bf1 + l * 512,
                                                   Wf2 + (size_t)l * 512 * 128, Pbuf);
    }
    classifier_kernel<<<1, 64, 0, stream>>>(tbuf, Pbuf, Wc, bc, (float*)d_out);
}